// Round 1
// baseline (451.353 us; speedup 1.0000x reference)
//
#include <hip/hip_runtime.h>
#include <hip/hip_bf16.h>
#include <math.h>

#define D 128
#define AGG_THREADS 128
#define CHUNK 512

// ---------------- el/er: per-node dot with attention vector ----------------
// One wave (64 lanes) per node; each lane loads a float2 (128 floats/row).
__global__ void dot_attn_kernel(const float* __restrict__ feat,
                                const float* __restrict__ attn,
                                float* __restrict__ out, int N) {
    int wave = threadIdx.x >> 6;            // 0..3
    int lane = threadIdx.x & 63;
    int node = blockIdx.x * 4 + wave;
    if (node >= N) return;
    const float2* row = (const float2*)(feat + (size_t)node * D);
    float2 a = ((const float2*)attn)[lane];
    float2 v = row[lane];
    float s = v.x * a.x + v.y * a.y;
    #pragma unroll
    for (int off = 32; off > 0; off >>= 1)
        s += __shfl_down(s, off, 64);
    if (lane == 0) out[node] = s;
}

// ---------------- histogram of dst ----------------
__global__ void hist_kernel(const int* __restrict__ dst, int E, int* __restrict__ counts) {
    int stride = gridDim.x * blockDim.x;
    for (int k = blockIdx.x * blockDim.x + threadIdx.x; k < E; k += stride)
        atomicAdd(&counts[dst[k]], 1);
}

// ---------------- 3-kernel exclusive scan ----------------
__global__ void scan1_kernel(const int* __restrict__ counts, int* __restrict__ offsets,
                             int* __restrict__ blockSums, int N) {
    __shared__ int tile[256];
    int tid = threadIdx.x;
    int i = blockIdx.x * 256 + tid;
    int v = (i < N) ? counts[i] : 0;
    tile[tid] = v;
    __syncthreads();
    for (int off = 1; off < 256; off <<= 1) {
        int t = (tid >= off) ? tile[tid - off] : 0;
        __syncthreads();
        tile[tid] += t;
        __syncthreads();
    }
    int incl = tile[tid];
    if (i < N) offsets[i] = incl - v;          // exclusive within block
    if (tid == 255) blockSums[blockIdx.x] = incl;
}

__global__ void scan2_kernel(int* __restrict__ bs, int nb) {
    __shared__ int tile[256];
    int tid = threadIdx.x;
    int carry = 0;
    for (int base = 0; base < nb; base += 256) {
        int i = base + tid;
        int v = (i < nb) ? bs[i] : 0;
        __syncthreads();
        tile[tid] = v;
        __syncthreads();
        for (int off = 1; off < 256; off <<= 1) {
            int t = (tid >= off) ? tile[tid - off] : 0;
            __syncthreads();
            tile[tid] += t;
            __syncthreads();
        }
        int incl = tile[tid];
        if (i < nb) bs[i] = incl - v + carry;  // exclusive + carry
        carry += tile[255];
    }
}

__global__ void scan3_kernel(int* __restrict__ offsets, const int* __restrict__ blockSums, int N) {
    int i = blockIdx.x * 256 + threadIdx.x;
    if (i < N) offsets[i] += blockSums[blockIdx.x];
}

// ---------------- fill CSR permutation (store src id per slot) ----------------
__global__ void fill_kernel(const int* __restrict__ src, const int* __restrict__ dst, int E,
                            const int* __restrict__ offsets, int* __restrict__ cursor,
                            int* __restrict__ perm_src) {
    int stride = gridDim.x * blockDim.x;
    for (int k = blockIdx.x * blockDim.x + threadIdx.x; k < E; k += stride) {
        int j = dst[k];
        int p = offsets[j] + atomicAdd(&cursor[j], 1);
        perm_src[p] = src[k];
    }
}

// ---------------- block reductions (128 threads = 2 waves) ----------------
__device__ __forceinline__ float block_max128(float v, float* red, int tid) {
    #pragma unroll
    for (int off = 32; off > 0; off >>= 1)
        v = fmaxf(v, __shfl_down(v, off, 64));
    __syncthreads();
    if ((tid & 63) == 0) red[tid >> 6] = v;
    __syncthreads();
    return fmaxf(red[0], red[1]);
}

__device__ __forceinline__ float block_sum128(float v, float* red, int tid) {
    #pragma unroll
    for (int off = 32; off > 0; off >>= 1)
        v += __shfl_down(v, off, 64);
    __syncthreads();
    if ((tid & 63) == 0) red[tid >> 6] = v;
    __syncthreads();
    return red[0] + red[1];
}

// ---------------- per-dst-node softmax + weighted aggregate ----------------
// One block of 128 threads per dst node; thread t owns feature t. No fp atomics.
__global__ void gat_aggregate_kernel(const float* __restrict__ feat_src,
                                     const float* __restrict__ el,
                                     const float* __restrict__ er,
                                     const int* __restrict__ offsets,
                                     const int* __restrict__ counts,
                                     const int* __restrict__ perm_src,
                                     float* __restrict__ out, int Nd) {
    __shared__ float w_sh[CHUNK];
    __shared__ int   s_sh[CHUNK];
    __shared__ float red[2];

    int j = blockIdx.x;
    int tid = threadIdx.x;
    int cnt = counts[j];
    size_t orow = (size_t)j * D;
    if (cnt == 0) { out[orow + tid] = 0.0f; return; }

    int beg = offsets[j];
    float erj = er[j];
    float acc = 0.0f;
    float inv;

    if (cnt <= CHUNK) {
        // fast path: edge scalars fit in LDS, one gather of el per edge
        float lmax = -INFINITY;
        for (int t = tid; t < cnt; t += AGG_THREADS) {
            int s = perm_src[beg + t];
            float e = el[s] + erj;
            e = (e >= 0.0f) ? e : 0.01f * e;   // leaky_relu
            s_sh[t] = s;
            w_sh[t] = e;
            lmax = fmaxf(lmax, e);
        }
        float m = block_max128(lmax, red, tid);
        float lsum = 0.0f;
        for (int t = tid; t < cnt; t += AGG_THREADS) {
            float a = __expf(w_sh[t] - m);
            w_sh[t] = a;
            lsum += a;
        }
        float den = block_sum128(lsum, red, tid);
        inv = 1.0f / den;
        __syncthreads();  // w_sh/s_sh visible to all
        int t = 0;
        for (; t + 4 <= cnt; t += 4) {
            float f0 = feat_src[(size_t)s_sh[t + 0] * D + tid];
            float f1 = feat_src[(size_t)s_sh[t + 1] * D + tid];
            float f2 = feat_src[(size_t)s_sh[t + 2] * D + tid];
            float f3 = feat_src[(size_t)s_sh[t + 3] * D + tid];
            acc += f0 * w_sh[t + 0] + f1 * w_sh[t + 1] + f2 * w_sh[t + 2] + f3 * w_sh[t + 3];
        }
        for (; t < cnt; ++t)
            acc += feat_src[(size_t)s_sh[t] * D + tid] * w_sh[t];
    } else {
        // generic path: recompute e, chunk through LDS
        float lmax = -INFINITY;
        for (int t = tid; t < cnt; t += AGG_THREADS) {
            int s = perm_src[beg + t];
            float e = el[s] + erj;
            e = (e >= 0.0f) ? e : 0.01f * e;
            lmax = fmaxf(lmax, e);
        }
        float m = block_max128(lmax, red, tid);
        float lsum = 0.0f;
        for (int t = tid; t < cnt; t += AGG_THREADS) {
            int s = perm_src[beg + t];
            float e = el[s] + erj;
            e = (e >= 0.0f) ? e : 0.01f * e;
            lsum += __expf(e - m);
        }
        float den = block_sum128(lsum, red, tid);
        inv = 1.0f / den;
        for (int base = 0; base < cnt; base += CHUNK) {
            int n = min(CHUNK, cnt - base);
            __syncthreads();
            for (int t = tid; t < n; t += AGG_THREADS) {
                int s = perm_src[beg + base + t];
                float e = el[s] + erj;
                e = (e >= 0.0f) ? e : 0.01f * e;
                s_sh[t] = s;
                w_sh[t] = __expf(e - m);
            }
            __syncthreads();
            for (int t = 0; t < n; ++t)
                acc += feat_src[(size_t)s_sh[t] * D + tid] * w_sh[t];
        }
    }
    out[orow + tid] = acc * inv;
}

extern "C" void kernel_launch(void* const* d_in, const int* in_sizes, int n_in,
                              void* d_out, int out_size, void* d_ws, size_t ws_size,
                              hipStream_t stream) {
    const float* feat_src = (const float*)d_in[0];
    const float* feat_dst = (const float*)d_in[1];
    const int*   src      = (const int*)d_in[2];
    const int*   dst      = (const int*)d_in[3];
    const float* attn_l   = (const float*)d_in[4];
    const float* attn_r   = (const float*)d_in[5];
    float* out = (float*)d_out;

    int Ns = in_sizes[0] / D;
    int Nd = in_sizes[1] / D;
    int E  = in_sizes[2];
    int nb = (Nd + 255) / 256;

    // workspace carve (256B aligned slices)
    char* p = (char*)d_ws;
    auto carve = [&](size_t bytes) { void* r = (void*)p; p += (bytes + 255) & ~(size_t)255; return r; };
    float* el        = (float*)carve((size_t)Ns * 4);
    float* er        = (float*)carve((size_t)Nd * 4);
    int*   counts    = (int*)carve((size_t)Nd * 4);
    int*   offsets   = (int*)carve((size_t)Nd * 4);
    int*   cursor    = (int*)carve((size_t)Nd * 4);
    int*   blockSums = (int*)carve((size_t)nb * 4);
    int*   perm_src  = (int*)carve((size_t)E * 4);

    hipMemsetAsync(counts, 0, (size_t)Nd * 4, stream);
    hipMemsetAsync(cursor, 0, (size_t)Nd * 4, stream);

    dot_attn_kernel<<<(Ns + 3) / 4, 256, 0, stream>>>(feat_src, attn_l, el, Ns);
    dot_attn_kernel<<<(Nd + 3) / 4, 256, 0, stream>>>(feat_dst, attn_r, er, Nd);
    hist_kernel<<<2048, 256, 0, stream>>>(dst, E, counts);
    scan1_kernel<<<nb, 256, 0, stream>>>(counts, offsets, blockSums, Nd);
    scan2_kernel<<<1, 256, 0, stream>>>(blockSums, nb);
    scan3_kernel<<<nb, 256, 0, stream>>>(offsets, blockSums, Nd);
    fill_kernel<<<2048, 256, 0, stream>>>(src, dst, E, offsets, cursor, perm_src);
    gat_aggregate_kernel<<<Nd, AGG_THREADS, 0, stream>>>(feat_src, el, er, offsets,
                                                         counts, perm_src, out, Nd);
}

// Round 2
// 407.787 us; speedup vs baseline: 1.1068x; 1.1068x over previous
//
#include <hip/hip_runtime.h>
#include <hip/hip_bf16.h>
#include <math.h>

#define D 128
#define AGG_THREADS 128
#define CHUNK 512

// ---------- helpers ----------
__device__ __forceinline__ unsigned short f2bf(float f) {
    union { float f; unsigned int u; } c; c.f = f;
    unsigned int u = c.u;
    unsigned int r = (u + 0x7FFFu + ((u >> 16) & 1u)) >> 16;  // RNE
    return (unsigned short)r;
}
__device__ __forceinline__ void unpack2(unsigned int w, float& lo, float& hi) {
    union { unsigned int u; float f; } c;
    c.u = w << 16;          lo = c.f;
    c.u = w & 0xFFFF0000u;  hi = c.f;
}

// ---------- prep: el = feat_src . attn_l, er = feat_dst . attn_r, bf16 copy of feat_src ----------
// One wave per node over the combined [Ns + Nd] index space (wave-uniform branch).
__global__ void prep_kernel(const float* __restrict__ feat_src,
                            const float* __restrict__ feat_dst,
                            const float* __restrict__ attn_l,
                            const float* __restrict__ attn_r,
                            float* __restrict__ el, float* __restrict__ er,
                            unsigned short* __restrict__ feat_bf, int store_bf,
                            int Ns, int Nd) {
    int wave = threadIdx.x >> 6;
    int lane = threadIdx.x & 63;
    int node = blockIdx.x * 4 + wave;
    if (node >= Ns + Nd) return;
    bool is_src = node < Ns;
    const float* feat = is_src ? feat_src + (size_t)node * D
                               : feat_dst + (size_t)(node - Ns) * D;
    const float* attn = is_src ? attn_l : attn_r;
    float2 a = ((const float2*)attn)[lane];
    float2 v = ((const float2*)feat)[lane];
    if (is_src && store_bf) {
        ushort2 h; h.x = f2bf(v.x); h.y = f2bf(v.y);
        ((ushort2*)(feat_bf + (size_t)node * D))[lane] = h;
    }
    float s = v.x * a.x + v.y * a.y;
    #pragma unroll
    for (int off = 32; off > 0; off >>= 1)
        s += __shfl_down(s, off, 64);
    if (lane == 0) {
        if (is_src) el[node] = s;
        else        er[node - Ns] = s;
    }
}

// ---------- histogram of dst ----------
__global__ void hist_kernel(const int* __restrict__ dst, int E, int* __restrict__ counts) {
    int stride = gridDim.x * blockDim.x;
    for (int k = blockIdx.x * blockDim.x + threadIdx.x; k < E; k += stride)
        atomicAdd(&counts[dst[k]], 1);
}

// ---------- 3-kernel exclusive scan ----------
__global__ void scan1_kernel(const int* __restrict__ counts, int* __restrict__ offsets,
                             int* __restrict__ blockSums, int N) {
    __shared__ int tile[256];
    int tid = threadIdx.x;
    int i = blockIdx.x * 256 + tid;
    int v = (i < N) ? counts[i] : 0;
    tile[tid] = v;
    __syncthreads();
    for (int off = 1; off < 256; off <<= 1) {
        int t = (tid >= off) ? tile[tid - off] : 0;
        __syncthreads();
        tile[tid] += t;
        __syncthreads();
    }
    int incl = tile[tid];
    if (i < N) offsets[i] = incl - v;
    if (tid == 255) blockSums[blockIdx.x] = incl;
}

__global__ void scan2_kernel(int* __restrict__ bs, int nb) {
    __shared__ int tile[256];
    int tid = threadIdx.x;
    int carry = 0;
    for (int base = 0; base < nb; base += 256) {
        int i = base + tid;
        int v = (i < nb) ? bs[i] : 0;
        __syncthreads();
        tile[tid] = v;
        __syncthreads();
        for (int off = 1; off < 256; off <<= 1) {
            int t = (tid >= off) ? tile[tid - off] : 0;
            __syncthreads();
            tile[tid] += t;
            __syncthreads();
        }
        int incl = tile[tid];
        if (i < nb) bs[i] = incl - v + carry;
        carry += tile[255];
    }
}

__global__ void scan3_kernel(int* __restrict__ offsets, const int* __restrict__ blockSums, int N) {
    int i = blockIdx.x * 256 + threadIdx.x;
    if (i < N) offsets[i] += blockSums[blockIdx.x];
}

// ---------- fill CSR permutation ----------
__global__ void fill_kernel(const int* __restrict__ src, const int* __restrict__ dst, int E,
                            const int* __restrict__ offsets, int* __restrict__ cursor,
                            int* __restrict__ perm_src) {
    int stride = gridDim.x * blockDim.x;
    for (int k = blockIdx.x * blockDim.x + threadIdx.x; k < E; k += stride) {
        int j = dst[k];
        int p = offsets[j] + atomicAdd(&cursor[j], 1);
        perm_src[p] = src[k];
    }
}

// ---------- block reductions (128 threads = 2 waves) ----------
__device__ __forceinline__ float block_max128(float v, float* red, int tid) {
    #pragma unroll
    for (int off = 32; off > 0; off >>= 1)
        v = fmaxf(v, __shfl_down(v, off, 64));
    __syncthreads();
    if ((tid & 63) == 0) red[tid >> 6] = v;
    __syncthreads();
    return fmaxf(red[0], red[1]);
}
__device__ __forceinline__ float block_sum128(float v, float* red, int tid) {
    #pragma unroll
    for (int off = 32; off > 0; off >>= 1)
        v += __shfl_down(v, off, 64);
    __syncthreads();
    if ((tid & 63) == 0) red[tid >> 6] = v;
    __syncthreads();
    return red[0] + red[1];
}

// ---------- bf16-vectorized aggregate ----------
// One block (128 thr) per dst node. group g = tid>>4 (8 groups = 8 edges in flight),
// u = tid&15 owns features [u*8, u*8+8) via one uint4 (8 bf16, 16 B) load per edge.
__global__ void gat_aggregate_bf16_kernel(const unsigned short* __restrict__ feat_bf,
                                          const float* __restrict__ el,
                                          const float* __restrict__ er,
                                          const int* __restrict__ offsets,
                                          const int* __restrict__ counts,
                                          const int* __restrict__ perm_src,
                                          float* __restrict__ out, int Nd) {
    __shared__ float w_sh[CHUNK];
    __shared__ int   s_sh[CHUNK];
    __shared__ float red[2];
    __shared__ float acc_sh[8][D];

    int j = blockIdx.x;
    int tid = threadIdx.x;
    int cnt = counts[j];
    size_t orow = (size_t)j * D;
    if (cnt == 0) { out[orow + tid] = 0.0f; return; }

    int beg = offsets[j];
    float erj = er[j];
    int g = tid >> 4, u = tid & 15;
    float acc[8];
    #pragma unroll
    for (int k = 0; k < 8; ++k) acc[k] = 0.0f;
    float inv;
    const unsigned short* fb = feat_bf + (size_t)u * 8;

    if (cnt <= CHUNK) {
        float lmax = -INFINITY;
        for (int t = tid; t < cnt; t += AGG_THREADS) {
            int s = perm_src[beg + t];
            float e = el[s] + erj;
            e = (e >= 0.0f) ? e : 0.01f * e;  // leaky_relu
            s_sh[t] = s;
            w_sh[t] = e;
            lmax = fmaxf(lmax, e);
        }
        float m = block_max128(lmax, red, tid);
        float lsum = 0.0f;
        for (int t = tid; t < cnt; t += AGG_THREADS) {
            float a = __expf(w_sh[t] - m);
            w_sh[t] = a;
            lsum += a;
        }
        float den = block_sum128(lsum, red, tid);
        inv = 1.0f / den;
        __syncthreads();
        for (int t = g; t < cnt; t += 8) {
            int s = s_sh[t];
            float w = w_sh[t];
            uint4 v = *(const uint4*)(fb + (size_t)s * D);
            float f[8];
            unpack2(v.x, f[0], f[1]); unpack2(v.y, f[2], f[3]);
            unpack2(v.z, f[4], f[5]); unpack2(v.w, f[6], f[7]);
            #pragma unroll
            for (int k = 0; k < 8; ++k) acc[k] += w * f[k];
        }
    } else {
        // generic chunked path (recompute e)
        float lmax = -INFINITY;
        for (int t = tid; t < cnt; t += AGG_THREADS) {
            int s = perm_src[beg + t];
            float e = el[s] + erj;
            e = (e >= 0.0f) ? e : 0.01f * e;
            lmax = fmaxf(lmax, e);
        }
        float m = block_max128(lmax, red, tid);
        float lsum = 0.0f;
        for (int t = tid; t < cnt; t += AGG_THREADS) {
            int s = perm_src[beg + t];
            float e = el[s] + erj;
            e = (e >= 0.0f) ? e : 0.01f * e;
            lsum += __expf(e - m);
        }
        float den = block_sum128(lsum, red, tid);
        inv = 1.0f / den;
        for (int base = 0; base < cnt; base += CHUNK) {
            int n = min(CHUNK, cnt - base);
            __syncthreads();
            for (int t = tid; t < n; t += AGG_THREADS) {
                int s = perm_src[beg + base + t];
                float e = el[s] + erj;
                e = (e >= 0.0f) ? e : 0.01f * e;
                s_sh[t] = s;
                w_sh[t] = __expf(e - m);
            }
            __syncthreads();
            for (int t = g; t < n; t += 8) {
                int s = s_sh[t];
                float w = w_sh[t];
                uint4 v = *(const uint4*)(fb + (size_t)s * D);
                float f[8];
                unpack2(v.x, f[0], f[1]); unpack2(v.y, f[2], f[3]);
                unpack2(v.z, f[4], f[5]); unpack2(v.w, f[6], f[7]);
                #pragma unroll
                for (int k = 0; k < 8; ++k) acc[k] += w * f[k];
            }
        }
    }
    // reduce the 8 edge-groups
    #pragma unroll
    for (int k = 0; k < 8; ++k) acc_sh[g][u * 8 + k] = acc[k];
    __syncthreads();
    float r = 0.0f;
    #pragma unroll
    for (int g2 = 0; g2 < 8; ++g2) r += acc_sh[g2][tid];
    out[orow + tid] = r * inv;
}

// ---------- fp32 fallback aggregate (proven R1 kernel) ----------
__global__ void gat_aggregate_f32_kernel(const float* __restrict__ feat_src,
                                         const float* __restrict__ el,
                                         const float* __restrict__ er,
                                         const int* __restrict__ offsets,
                                         const int* __restrict__ counts,
                                         const int* __restrict__ perm_src,
                                         float* __restrict__ out, int Nd) {
    __shared__ float w_sh[CHUNK];
    __shared__ int   s_sh[CHUNK];
    __shared__ float red[2];

    int j = blockIdx.x;
    int tid = threadIdx.x;
    int cnt = counts[j];
    size_t orow = (size_t)j * D;
    if (cnt == 0) { out[orow + tid] = 0.0f; return; }

    int beg = offsets[j];
    float erj = er[j];
    float acc = 0.0f;
    float inv;

    if (cnt <= CHUNK) {
        float lmax = -INFINITY;
        for (int t = tid; t < cnt; t += AGG_THREADS) {
            int s = perm_src[beg + t];
            float e = el[s] + erj;
            e = (e >= 0.0f) ? e : 0.01f * e;
            s_sh[t] = s;
            w_sh[t] = e;
            lmax = fmaxf(lmax, e);
        }
        float m = block_max128(lmax, red, tid);
        float lsum = 0.0f;
        for (int t = tid; t < cnt; t += AGG_THREADS) {
            float a = __expf(w_sh[t] - m);
            w_sh[t] = a;
            lsum += a;
        }
        float den = block_sum128(lsum, red, tid);
        inv = 1.0f / den;
        __syncthreads();
        int t = 0;
        for (; t + 4 <= cnt; t += 4) {
            float f0 = feat_src[(size_t)s_sh[t + 0] * D + tid];
            float f1 = feat_src[(size_t)s_sh[t + 1] * D + tid];
            float f2 = feat_src[(size_t)s_sh[t + 2] * D + tid];
            float f3 = feat_src[(size_t)s_sh[t + 3] * D + tid];
            acc += f0 * w_sh[t + 0] + f1 * w_sh[t + 1] + f2 * w_sh[t + 2] + f3 * w_sh[t + 3];
        }
        for (; t < cnt; ++t)
            acc += feat_src[(size_t)s_sh[t] * D + tid] * w_sh[t];
    } else {
        float lmax = -INFINITY;
        for (int t = tid; t < cnt; t += AGG_THREADS) {
            int s = perm_src[beg + t];
            float e = el[s] + erj;
            e = (e >= 0.0f) ? e : 0.01f * e;
            lmax = fmaxf(lmax, e);
        }
        float m = block_max128(lmax, red, tid);
        float lsum = 0.0f;
        for (int t = tid; t < cnt; t += AGG_THREADS) {
            int s = perm_src[beg + t];
            float e = el[s] + erj;
            e = (e >= 0.0f) ? e : 0.01f * e;
            lsum += __expf(e - m);
        }
        float den = block_sum128(lsum, red, tid);
        inv = 1.0f / den;
        for (int base = 0; base < cnt; base += CHUNK) {
            int n = min(CHUNK, cnt - base);
            __syncthreads();
            for (int t = tid; t < n; t += AGG_THREADS) {
                int s = perm_src[beg + base + t];
                float e = el[s] + erj;
                e = (e >= 0.0f) ? e : 0.01f * e;
                s_sh[t] = s;
                w_sh[t] = __expf(e - m);
            }
            __syncthreads();
            for (int t = 0; t < n; ++t)
                acc += feat_src[(size_t)s_sh[t] * D + tid] * w_sh[t];
        }
    }
    out[orow + tid] = acc * inv;
}

extern "C" void kernel_launch(void* const* d_in, const int* in_sizes, int n_in,
                              void* d_out, int out_size, void* d_ws, size_t ws_size,
                              hipStream_t stream) {
    const float* feat_src = (const float*)d_in[0];
    const float* feat_dst = (const float*)d_in[1];
    const int*   src      = (const int*)d_in[2];
    const int*   dst      = (const int*)d_in[3];
    const float* attn_l   = (const float*)d_in[4];
    const float* attn_r   = (const float*)d_in[5];
    float* out = (float*)d_out;

    int Ns = in_sizes[0] / D;
    int Nd = in_sizes[1] / D;
    int E  = in_sizes[2];
    int nb = (Nd + 255) / 256;

    // workspace carve (256B aligned slices); counts+cursor adjacent for one memset
    char* p = (char*)d_ws;
    auto carve = [&](size_t bytes) { void* r = (void*)p; p += (bytes + 255) & ~(size_t)255; return r; };
    float* el        = (float*)carve((size_t)Ns * 4);
    float* er        = (float*)carve((size_t)Nd * 4);
    int*   counts    = (int*)carve((size_t)Nd * 4);
    int*   cursor    = (int*)carve((size_t)Nd * 4);
    int*   offsets   = (int*)carve((size_t)Nd * 4);
    int*   blockSums = (int*)carve((size_t)nb * 4);
    int*   perm_src  = (int*)carve((size_t)E * 4);
    size_t base_used = (size_t)(p - (char*)d_ws);
    size_t bf_bytes  = (size_t)Ns * D * 2;
    int use_bf16 = (base_used + bf_bytes + 256 <= ws_size) ? 1 : 0;
    unsigned short* feat_bf = use_bf16 ? (unsigned short*)carve(bf_bytes) : nullptr;

    // zero counts + cursor in one memset (they are adjacent)
    hipMemsetAsync(counts, 0, (size_t)((char*)offsets - (char*)counts), stream);

    int total = Ns + Nd;
    prep_kernel<<<(total + 3) / 4, 256, 0, stream>>>(feat_src, feat_dst, attn_l, attn_r,
                                                     el, er, feat_bf, use_bf16, Ns, Nd);
    hist_kernel<<<2048, 256, 0, stream>>>(dst, E, counts);
    scan1_kernel<<<nb, 256, 0, stream>>>(counts, offsets, blockSums, Nd);
    scan2_kernel<<<1, 256, 0, stream>>>(blockSums, nb);
    scan3_kernel<<<nb, 256, 0, stream>>>(offsets, blockSums, Nd);
    fill_kernel<<<2048, 256, 0, stream>>>(src, dst, E, offsets, cursor, perm_src);
    if (use_bf16) {
        gat_aggregate_bf16_kernel<<<Nd, AGG_THREADS, 0, stream>>>(feat_bf, el, er, offsets,
                                                                  counts, perm_src, out, Nd);
    } else {
        gat_aggregate_f32_kernel<<<Nd, AGG_THREADS, 0, stream>>>(feat_src, el, er, offsets,
                                                                 counts, perm_src, out, Nd);
    }
}